// Round 5
// baseline (150.094 us; speedup 1.0000x reference)
//
#include <hip/hip_runtime.h>

#define NB    256
#define SLEN  8192
#define LOG2S 13
#define TOPK  10

// Real-only layout (harness counts complex64 as ONE element):
//   bf real parts:   float [0, 256*10*8192)            = [0, 20971520)
//   residual real:   float [20971520, 23068672)
#define RES_REAL   ((size_t)20971520)
#define FULL_ILV   ((size_t)46137344)   // fallback: interleaved re/im layout

// v_sin_f32 / v_cos_f32 take REVOLUTIONS; all args stay in (-0.1, 0.5).
__device__ __forceinline__ float sin_rev(float p) { return __builtin_amdgcn_sinf(p); }
__device__ __forceinline__ float cos_rev(float p) { return __builtin_amdgcn_cosf(p); }

// challenger (om,oi) beats (wm,wi): strictly better wins; within 1e-4
// relative band the LOWER index wins (stable argsort of conjugate-pair ties).
__device__ __forceinline__ bool beats(float om, int oi, float wm, int wi) {
  return (om > wm * 1.0001f) || (om > wm * 0.9999f && oi < wi);
}

// Padded LDS index: +a/32 breaks every power-of-2 stride bank pattern.
__device__ __forceinline__ int pad(int a) { return a + (a >> 5); }

// Nontemporal float4 store (output is never re-read by us -> skip L2 alloc).
typedef float f32x4 __attribute__((ext_vector_type(4)));
__device__ __forceinline__ void store_nt4(float* p, float a, float b, float c,
                                          float d) {
  f32x4 v = {a, b, c, d};
  __builtin_nontemporal_store(v, (f32x4*)p);
}

// One DIF butterfly: u' = u + v ; v' = (u - v) * exp(-2*pi*i*p)
__device__ __forceinline__ void bfly(float& ur, float& ui, float& vr, float& vi,
                                     float p) {
  const float c = cos_rev(p);
  const float s = -sin_rev(p);
  const float dr = ur - vr, di = ui - vi;
  ur += vr; ui += vi;
  vr = dr * c - di * s;
  vi = dr * s + di * c;
}

// Three DIF stages on 8 in-register elements i = i0 + ST*k (k=0..7),
// m = i0 mod ST. Stage distances (in elements): 4*ST, 2*ST, ST.
template<int ST>
__device__ __forceinline__ void bfly3(float (&xr)[8], float (&xi)[8], int m) {
  const float inv8 = 1.f / (float)(ST * 8);
  const float inv4 = 1.f / (float)(ST * 4);
  const float inv2 = 1.f / (float)(ST * 2);
#pragma unroll
  for (int k = 0; k < 4; ++k)                       // h = 4*ST: (k, k+4)
    bfly(xr[k], xi[k], xr[k + 4], xi[k + 4], (float)(m + ST * k) * inv8);
#pragma unroll
  for (int g = 0; g < 2; ++g)                       // h = 2*ST: (k, k+2)
#pragma unroll
    for (int k0 = 0; k0 < 2; ++k0) {
      const int k = g * 4 + k0;
      bfly(xr[k], xi[k], xr[k + 2], xi[k + 2], (float)(m + ST * k0) * inv4);
    }
  const float p1 = (float)m * inv2;                 // h = ST: (k, k+1)
#pragma unroll
  for (int k = 0; k < 8; k += 2)
    bfly(xr[k], xi[k], xr[k + 1], xi[k + 1], p1);
}

// ------------- Fused kernel: FFT + top-10 + generation (1 block/batch) -----
// Radix-8 register-blocked DIF FFT: natural-order input, bit-reversed output.
// LDS holds interleaved complex (float2) -> all exchanges are ds_*_b64.
__global__ __launch_bounds__(1024)
void fourier_all(const float* __restrict__ x, float* __restrict__ out,
                 size_t cap) {
  __shared__ float2 Z[8448];                        // pad(8191)=8446 < 8448
  __shared__ float  wred_m[2][16];                  // double-buffered by round
  __shared__ int    wred_i[2][16];
  __shared__ int    sk[TOPK];                       // winner broadcast
  __shared__ float  sar[TOPK], sai[TOPK];

  const int b = blockIdx.x;
  const int t = threadIdx.x;                        // 0..1023
  const int lane = t & 63;
  const int wid  = t >> 6;                          // 16 waves
  const float* xb = x + (size_t)b * SLEN;

  float xr[8], xi[8];

  // ---- Phase A: stages h=4096,2048,1024. Elements i = t + 1024k,
  //      loaded straight from global (coalesced, 64 consecutive floats/wave).
#pragma unroll
  for (int k = 0; k < 8; ++k) { xr[k] = xb[t + (k << 10)]; xi[k] = 0.f; }
  bfly3<1024>(xr, xi, t);
#pragma unroll
  for (int k = 0; k < 8; ++k)
    Z[pad(t + (k << 10))] = make_float2(xr[k], xi[k]);
  __syncthreads();

  // ---- Phase B: stages h=512,256,128. i = (t&127) + (t>>7)*1024 + 128k.
  {
    const int m  = t & 127;
    const int i0 = m + ((t >> 7) << 10);
#pragma unroll
    for (int k = 0; k < 8; ++k) {
      const float2 v = Z[pad(i0 + (k << 7))];
      xr[k] = v.x; xi[k] = v.y;
    }
    bfly3<128>(xr, xi, m);
#pragma unroll
    for (int k = 0; k < 8; ++k)
      Z[pad(i0 + (k << 7))] = make_float2(xr[k], xi[k]);
  }
  __syncthreads();

  // ---- Phase C: stages h=64,32,16. i = (t&15) + (t>>4)*128 + 16k.
  {
    const int m  = t & 15;
    const int i0 = m + ((t >> 4) << 7);
#pragma unroll
    for (int k = 0; k < 8; ++k) {
      const float2 v = Z[pad(i0 + (k << 4))];
      xr[k] = v.x; xi[k] = v.y;
    }
    bfly3<16>(xr, xi, m);
#pragma unroll
    for (int k = 0; k < 8; ++k)
      Z[pad(i0 + (k << 4))] = make_float2(xr[k], xi[k]);
  }
  __syncthreads();

  // ---- Phase D: stages h=8,4,2. i = (t&1) + (t>>1)*16 + 2k.
  {
    const int m  = t & 1;
    const int i0 = m + ((t >> 1) << 4);
#pragma unroll
    for (int k = 0; k < 8; ++k) {
      const float2 v = Z[pad(i0 + (k << 1))];
      xr[k] = v.x; xi[k] = v.y;
    }
    bfly3<2>(xr, xi, m);
#pragma unroll
    for (int k = 0; k < 8; ++k)
      Z[pad(i0 + (k << 1))] = make_float2(xr[k], xi[k]);
  }
  __syncthreads();

  // ---- Phase E: final stage h=1 (twiddle-free), storage pos p = 8t+q.
  //      Results stay in REGISTERS; frequency f = bitrev13(p).
#pragma unroll
  for (int q = 0; q < 8; ++q) {
    const float2 v = Z[pad((t << 3) + q)];
    xr[q] = v.x; xi[q] = v.y;
  }
#pragma unroll
  for (int q = 0; q < 8; q += 2) {
    const float ur = xr[q], ui = xi[q];
    const float vr = xr[q + 1], vi = xi[q + 1];
    xr[q] = ur + vr;     xi[q] = ui + vi;
    xr[q + 1] = ur - vr; xi[q + 1] = ui - vi;
  }

  float m2c[8];
#pragma unroll
  for (int q = 0; q < 8; ++q) m2c[q] = xr[q] * xr[q] + xi[q] * xi[q];

  // slot q holds frequency f = bitrev10(t) + 1024*bitrev3(q)
  const int rt = (int)(__brev((unsigned)t) >> 22);  // bitrev10(t)
  const int qord[8] = {0, 4, 2, 6, 1, 5, 3, 7};     // bitrev3 ascending

  // ---- 10 selection rounds; 1 barrier/round, shfl-tree block reduce ----
  for (int sel = 0; sel < TOPK; ++sel) {
    float wm = -1.f; int wi = SLEN;
#pragma unroll
    for (int j = 0; j < 8; ++j) {                   // ascending frequency
      const int q = qord[j];
      if (m2c[q] > wm * 1.0001f) { wm = m2c[q]; wi = rt + (j << 10); }
    }
    for (int off = 32; off > 0; off >>= 1) {        // 64-lane wave reduction
      const float om = __shfl_down(wm, off);
      const int   oi = __shfl_down(wi, off);
      if (beats(om, oi, wm, wi)) { wm = om; wi = oi; }
    }
    const int par = sel & 1;
    if (lane == 0) { wred_m[par][wid] = wm; wred_i[par][wid] = wi; }
    __syncthreads();
    // every wave redundantly reduces the 16 wave-winners via shfl tree
    float cm = -1.f; int ci = SLEN;
    if (lane < 16) { cm = wred_m[par][lane]; ci = wred_i[par][lane]; }
    for (int off = 8; off > 0; off >>= 1) {
      const float om = __shfl_down(cm, off);
      const int   oi = __shfl_down(ci, off);
      if (beats(om, oi, cm, ci)) { cm = om; ci = oi; }
    }
    wm = __shfl(cm, 0); wi = __shfl(ci, 0);         // broadcast block winner
    // winner's OWNER thread records coefficients + excludes it
    const int p = (int)(__brev((unsigned)wi) >> 19);  // pos = bitrev13(f)
    if ((p >> 3) == t) {
      const int q = p & 7;
      // a_j = raw[k]/S * exp(-2*pi*i*k*1e-5)
      const float rr = xr[q] * (1.f / (float)SLEN);
      const float ii = xi[q] * (1.f / (float)SLEN);
      const float pr = -1e-5f * (float)wi;          // revolutions, |pr|<=0.082
      const float cp = cos_rev(pr), sp = sin_rev(pr);
      sk [sel] = wi;
      sar[sel] = rr * cp - ii * sp;
      sai[sel] = rr * sp + ii * cp;
      m2c[q] = 0.f;
    }
    // no second barrier: next round writes the OTHER parity buffer, whose
    // previous readers are two barriers back.
  }
  __syncthreads();                                  // all sk/sar/sai visible

  // ---- Generation (fused): thread t owns s = 8t .. 8t+7 ----
  // Re bf[b,j,s] = ar*cos(2pi k m/S) - ai*sin(.), m = max(s,1)
  // residual_re[b,s] = x[b,s] - sum_j Re bf
  int kj[TOPK]; float arj[TOPK], aij[TOPK];
#pragma unroll
  for (int j = 0; j < TOPK; ++j) {
    kj[j] = sk[j]; arj[j] = sar[j]; aij[j] = sai[j];
  }
  const int s0 = t << 3;

  if (cap < FULL_ILV) {
    // PRIMARY: real-part-only layout
    const size_t bfbase = (size_t)b * TOPK * SLEN;
    const float4 xv0 = *(const float4*)(xb + s0);
    const float4 xv1 = *(const float4*)(xb + s0 + 4);
    float acc[8];
#pragma unroll
    for (int q = 0; q < 8; ++q) acc[q] = 0.f;
#pragma unroll
    for (int j = 0; j < TOPK; ++j) {
      const int k = kj[j];
      float br[8];
#pragma unroll
      for (int q = 0; q < 8; ++q) {
        const int s = s0 + q;
        const int m = (s == 0) ? 1 : s;
        const float p = (float)((k * m) & (SLEN - 1)) * (1.f / (float)SLEN);
        br[q] = arj[j] * cos_rev(p) - aij[j] * sin_rev(p);
        acc[q] += br[q];
      }
      const size_t o = bfbase + (size_t)j * SLEN + s0;
      if (o + 8 <= cap) {
        store_nt4(out + o,     br[0], br[1], br[2], br[3]);
        store_nt4(out + o + 4, br[4], br[5], br[6], br[7]);
      }
    }
    const size_t o = RES_REAL + (size_t)b * SLEN + s0;
    if (o + 8 <= cap) {
      store_nt4(out + o,     xv0.x - acc[0], xv0.y - acc[1], xv0.z - acc[2],
                xv0.w - acc[3]);
      store_nt4(out + o + 4, xv1.x - acc[4], xv1.y - acc[5], xv1.z - acc[6],
                xv1.w - acc[7]);
    }
  } else {
    // FALLBACK: interleaved complex layout (if out_size counts floats)
    const size_t bfbase = (size_t)b * TOPK * SLEN * 2;
    const float4 xv0 = *(const float4*)(xb + s0);
    const float4 xv1 = *(const float4*)(xb + s0 + 4);
    const float xs[8] = {xv0.x, xv0.y, xv0.z, xv0.w, xv1.x, xv1.y, xv1.z, xv1.w};
    float sr[8], si[8];
#pragma unroll
    for (int q = 0; q < 8; ++q) { sr[q] = 0.f; si[q] = 0.f; }
#pragma unroll
    for (int j = 0; j < TOPK; ++j) {
      const int k = kj[j];
      float br[8], bi[8];
#pragma unroll
      for (int q = 0; q < 8; ++q) {
        const int s = s0 + q;
        const int m = (s == 0) ? 1 : s;
        const float p = (float)((k * m) & (SLEN - 1)) * (1.f / (float)SLEN);
        const float c = cos_rev(p), sv = sin_rev(p);
        br[q] = arj[j] * c - aij[j] * sv;
        bi[q] = arj[j] * sv + aij[j] * c;
        sr[q] += br[q]; si[q] += bi[q];
      }
      const size_t o = bfbase + ((size_t)j * SLEN + s0) * 2;
      if (o + 16 <= cap) {
        store_nt4(out + o,      br[0], bi[0], br[1], bi[1]);
        store_nt4(out + o + 4,  br[2], bi[2], br[3], bi[3]);
        store_nt4(out + o + 8,  br[4], bi[4], br[5], bi[5]);
        store_nt4(out + o + 12, br[6], bi[6], br[7], bi[7]);
      }
    }
    const size_t o = (size_t)41943040 + ((size_t)b * SLEN + s0) * 2;
    if (o + 16 <= cap) {
      store_nt4(out + o,      xs[0] - sr[0], -si[0], xs[1] - sr[1], -si[1]);
      store_nt4(out + o + 4,  xs[2] - sr[2], -si[2], xs[3] - sr[3], -si[3]);
      store_nt4(out + o + 8,  xs[4] - sr[4], -si[4], xs[5] - sr[5], -si[5]);
      store_nt4(out + o + 12, xs[6] - sr[6], -si[6], xs[7] - sr[7], -si[7]);
    }
  }
}

extern "C" void kernel_launch(void* const* d_in, const int* in_sizes, int n_in,
                              void* d_out, int out_size, void* d_ws, size_t ws_size,
                              hipStream_t stream) {
  const float* x = (const float*)d_in[0];
  float* out = (float*)d_out;
  fourier_all<<<NB, 1024, 0, stream>>>(x, out, (size_t)out_size);
}

// Round 6
// 122.955 us; speedup vs baseline: 1.2207x; 1.2207x over previous
//
#include <hip/hip_runtime.h>

#define NB    256
#define SLEN  8192
#define LOG2S 13
#define TOPK  10

// Real-only layout (harness counts complex64 as ONE element):
//   bf real parts:   float [0, 256*10*8192)            = [0, 20971520)
//   residual real:   float [20971520, 23068672)
#define RES_REAL   ((size_t)20971520)
#define FULL_ILV   ((size_t)46137344)   // fallback: interleaved re/im layout

// Per-batch top-10 coefficients, produced by fft_topk, consumed by gen.
__device__ int   g_k [NB * TOPK];
__device__ float g_ar[NB * TOPK];
__device__ float g_ai[NB * TOPK];

// v_sin_f32 / v_cos_f32 take REVOLUTIONS; all args stay in (-0.1, 0.5).
__device__ __forceinline__ float sin_rev(float p) { return __builtin_amdgcn_sinf(p); }
__device__ __forceinline__ float cos_rev(float p) { return __builtin_amdgcn_cosf(p); }

// challenger (om,oi) beats (wm,wi): strictly better wins; within 1e-4
// relative band the LOWER index wins (stable argsort of conjugate-pair ties).
__device__ __forceinline__ bool beats(float om, int oi, float wm, int wi) {
  return (om > wm * 1.0001f) || (om > wm * 0.9999f && oi < wi);
}

// Padded LDS index: +a/32 breaks every power-of-2 stride bank pattern.
__device__ __forceinline__ int pad(int a) { return a + (a >> 5); }

// Nontemporal float4 store (output is never re-read by us -> skip L2 alloc).
typedef float f32x4 __attribute__((ext_vector_type(4)));
__device__ __forceinline__ void store_nt4(float* p, float a, float b, float c,
                                          float d) {
  f32x4 v = {a, b, c, d};
  __builtin_nontemporal_store(v, (f32x4*)p);
}

// One DIF butterfly: u' = u + v ; v' = (u - v) * exp(-2*pi*i*p)
__device__ __forceinline__ void bfly(float& ur, float& ui, float& vr, float& vi,
                                     float p) {
  const float c = cos_rev(p);
  const float s = -sin_rev(p);
  const float dr = ur - vr, di = ui - vi;
  ur += vr; ui += vi;
  vr = dr * c - di * s;
  vi = dr * s + di * c;
}

// Three DIF stages on 8 in-register elements i = i0 + ST*k (k=0..7),
// m = i0 mod ST. Stage distances (in elements): 4*ST, 2*ST, ST.
template<int ST>
__device__ __forceinline__ void bfly3(float (&xr)[8], float (&xi)[8], int m) {
  const float inv8 = 1.f / (float)(ST * 8);
  const float inv4 = 1.f / (float)(ST * 4);
  const float inv2 = 1.f / (float)(ST * 2);
#pragma unroll
  for (int k = 0; k < 4; ++k)                       // h = 4*ST: (k, k+4)
    bfly(xr[k], xi[k], xr[k + 4], xi[k + 4], (float)(m + ST * k) * inv8);
#pragma unroll
  for (int g = 0; g < 2; ++g)                       // h = 2*ST: (k, k+2)
#pragma unroll
    for (int k0 = 0; k0 < 2; ++k0) {
      const int k = g * 4 + k0;
      bfly(xr[k], xi[k], xr[k + 2], xi[k + 2], (float)(m + ST * k0) * inv4);
    }
  const float p1 = (float)m * inv2;                 // h = ST: (k, k+1)
#pragma unroll
  for (int k = 0; k < 8; k += 2)
    bfly(xr[k], xi[k], xr[k + 1], xi[k + 1], p1);
}

// ---------------- Kernel 1: FFT + top-10 (one block per batch) -------------
// Radix-8 register-blocked DIF FFT: natural-order input, bit-reversed output.
// LDS holds interleaved complex (float2) -> all exchanges are ds_*_b64.
__global__ __launch_bounds__(1024)
void fft_topk(const float* __restrict__ x) {
  __shared__ float2 Z[8448];                        // pad(8191)=8446 < 8448
  __shared__ float  wred_m[2][16];                  // double-buffered by round
  __shared__ int    wred_i[2][16];

  const int b = blockIdx.x;
  const int t = threadIdx.x;                        // 0..1023
  const int lane = t & 63;
  const int wid  = t >> 6;                          // 16 waves
  const float* xb = x + (size_t)b * SLEN;

  float xr[8], xi[8];

  // ---- Phase A: stages h=4096,2048,1024. Elements i = t + 1024k,
  //      loaded straight from global (coalesced, 64 consecutive floats/wave).
#pragma unroll
  for (int k = 0; k < 8; ++k) { xr[k] = xb[t + (k << 10)]; xi[k] = 0.f; }
  bfly3<1024>(xr, xi, t);
#pragma unroll
  for (int k = 0; k < 8; ++k)
    Z[pad(t + (k << 10))] = make_float2(xr[k], xi[k]);
  __syncthreads();

  // ---- Phase B: stages h=512,256,128. i = (t&127) + (t>>7)*1024 + 128k.
  {
    const int m  = t & 127;
    const int i0 = m + ((t >> 7) << 10);
#pragma unroll
    for (int k = 0; k < 8; ++k) {
      const float2 v = Z[pad(i0 + (k << 7))];
      xr[k] = v.x; xi[k] = v.y;
    }
    bfly3<128>(xr, xi, m);
#pragma unroll
    for (int k = 0; k < 8; ++k)
      Z[pad(i0 + (k << 7))] = make_float2(xr[k], xi[k]);
  }
  __syncthreads();

  // ---- Phase C: stages h=64,32,16. i = (t&15) + (t>>4)*128 + 16k.
  {
    const int m  = t & 15;
    const int i0 = m + ((t >> 4) << 7);
#pragma unroll
    for (int k = 0; k < 8; ++k) {
      const float2 v = Z[pad(i0 + (k << 4))];
      xr[k] = v.x; xi[k] = v.y;
    }
    bfly3<16>(xr, xi, m);
#pragma unroll
    for (int k = 0; k < 8; ++k)
      Z[pad(i0 + (k << 4))] = make_float2(xr[k], xi[k]);
  }
  __syncthreads();

  // ---- Phase D: stages h=8,4,2. i = (t&1) + (t>>1)*16 + 2k.
  {
    const int m  = t & 1;
    const int i0 = m + ((t >> 1) << 4);
#pragma unroll
    for (int k = 0; k < 8; ++k) {
      const float2 v = Z[pad(i0 + (k << 1))];
      xr[k] = v.x; xi[k] = v.y;
    }
    bfly3<2>(xr, xi, m);
#pragma unroll
    for (int k = 0; k < 8; ++k)
      Z[pad(i0 + (k << 1))] = make_float2(xr[k], xi[k]);
  }
  __syncthreads();

  // ---- Phase E: final stage h=1 (twiddle-free), storage pos p = 8t+q.
  //      Results stay in REGISTERS; frequency f = bitrev13(p).
#pragma unroll
  for (int q = 0; q < 8; ++q) {
    const float2 v = Z[pad((t << 3) + q)];
    xr[q] = v.x; xi[q] = v.y;
  }
#pragma unroll
  for (int q = 0; q < 8; q += 2) {
    const float ur = xr[q], ui = xi[q];
    const float vr = xr[q + 1], vi = xi[q + 1];
    xr[q] = ur + vr;     xi[q] = ui + vi;
    xr[q + 1] = ur - vr; xi[q + 1] = ui - vi;
  }

  float m2c[8];
#pragma unroll
  for (int q = 0; q < 8; ++q) m2c[q] = xr[q] * xr[q] + xi[q] * xi[q];

  // slot q holds frequency f = bitrev10(t) + 1024*bitrev3(q)
  const int rt = (int)(__brev((unsigned)t) >> 22);  // bitrev10(t)
  const int qord[8] = {0, 4, 2, 6, 1, 5, 3, 7};     // bitrev3 ascending

  // ---- 10 selection rounds; 1 barrier/round, shfl-tree block reduce ----
  for (int sel = 0; sel < TOPK; ++sel) {
    float wm = -1.f; int wi = SLEN;
#pragma unroll
    for (int j = 0; j < 8; ++j) {                   // ascending frequency
      const int q = qord[j];
      if (m2c[q] > wm * 1.0001f) { wm = m2c[q]; wi = rt + (j << 10); }
    }
    for (int off = 32; off > 0; off >>= 1) {        // 64-lane wave reduction
      const float om = __shfl_down(wm, off);
      const int   oi = __shfl_down(wi, off);
      if (beats(om, oi, wm, wi)) { wm = om; wi = oi; }
    }
    const int par = sel & 1;
    if (lane == 0) { wred_m[par][wid] = wm; wred_i[par][wid] = wi; }
    __syncthreads();
    // every wave redundantly reduces the 16 wave-winners via shfl tree
    float cm = -1.f; int ci = SLEN;
    if (lane < 16) { cm = wred_m[par][lane]; ci = wred_i[par][lane]; }
    for (int off = 8; off > 0; off >>= 1) {
      const float om = __shfl_down(cm, off);
      const int   oi = __shfl_down(ci, off);
      if (beats(om, oi, cm, ci)) { cm = om; ci = oi; }
    }
    wm = __shfl(cm, 0); wi = __shfl(ci, 0);         // broadcast block winner
    // winner's OWNER thread records coefficients + excludes it
    const int p = (int)(__brev((unsigned)wi) >> 19);  // pos = bitrev13(f)
    if ((p >> 3) == t) {
      const int q = p & 7;
      // a_j = raw[k]/S * exp(-2*pi*i*k*1e-5)
      const float rr = xr[q] * (1.f / (float)SLEN);
      const float ii = xi[q] * (1.f / (float)SLEN);
      const float pr = -1e-5f * (float)wi;          // revolutions, |pr|<=0.082
      const float cp = cos_rev(pr), sp = sin_rev(pr);
      g_k [b * TOPK + sel] = wi;
      g_ar[b * TOPK + sel] = rr * cp - ii * sp;
      g_ai[b * TOPK + sel] = rr * sp + ii * cp;
      m2c[q] = 0.f;
    }
    // no second barrier: next round writes the OTHER parity buffer, whose
    // previous readers are two barriers back.
  }
}

// ---------------- Kernel 2: generation (8 slices per batch) ----------------
// Re bf[b,j,s] = ar*cos(2pi k m/S) - ai*sin(.), m = max(s,1)
// residual_re[b,s] = x[b,s] - sum_j Re bf
// Kept separate from fft_topk: fusing it (round 5) forced a 64-VGPR fit,
// spilled the coefficient arrays, and ran stores at 1.5 TB/s instead of 6.2.
__global__ __launch_bounds__(256, 4)
void gen(const float* __restrict__ x, float* __restrict__ out, size_t cap) {
  const int bs    = blockIdx.x;
  const int b     = bs >> 3;
  const int slice = bs & 7;
  const int t     = threadIdx.x;
  const int s0    = slice * 1024 + t * 4;           // 4 consecutive s -> float4
  const float* xb = x + (size_t)b * SLEN;

  int kj[TOPK]; float arj[TOPK], aij[TOPK];
#pragma unroll
  for (int j = 0; j < TOPK; ++j) {
    kj[j]  = g_k [b * TOPK + j];
    arj[j] = g_ar[b * TOPK + j];
    aij[j] = g_ai[b * TOPK + j];
  }

  if (cap < FULL_ILV) {
    // PRIMARY: real-part-only layout
    const size_t bfbase = (size_t)b * TOPK * SLEN;
    const float4 xv = *(const float4*)(xb + s0);
    float acc0 = 0.f, acc1 = 0.f, acc2 = 0.f, acc3 = 0.f;
#pragma unroll
    for (int j = 0; j < TOPK; ++j) {
      const int k = kj[j];
      float br[4];
#pragma unroll
      for (int q = 0; q < 4; ++q) {
        const int s = s0 + q;
        const int m = (s == 0) ? 1 : s;
        const float p = (float)((k * m) & (SLEN - 1)) * (1.f / (float)SLEN);
        br[q] = arj[j] * cos_rev(p) - aij[j] * sin_rev(p);
      }
      acc0 += br[0]; acc1 += br[1]; acc2 += br[2]; acc3 += br[3];
      const size_t o = bfbase + (size_t)j * SLEN + s0;
      if (o + 4 <= cap)
        store_nt4(out + o, br[0], br[1], br[2], br[3]);
    }
    const size_t o = RES_REAL + (size_t)b * SLEN + s0;
    if (o + 4 <= cap)
      store_nt4(out + o, xv.x - acc0, xv.y - acc1, xv.z - acc2, xv.w - acc3);
  } else {
    // FALLBACK: interleaved complex layout (if out_size counts floats)
    const size_t bfbase = (size_t)b * TOPK * SLEN * 2;
    const float4 xv = *(const float4*)(xb + s0);
    float sr[4] = {0.f, 0.f, 0.f, 0.f}, si[4] = {0.f, 0.f, 0.f, 0.f};
#pragma unroll
    for (int j = 0; j < TOPK; ++j) {
      const int k = kj[j];
      float br[4], bi[4];
#pragma unroll
      for (int q = 0; q < 4; ++q) {
        const int s = s0 + q;
        const int m = (s == 0) ? 1 : s;
        const float p = (float)((k * m) & (SLEN - 1)) * (1.f / (float)SLEN);
        const float c = cos_rev(p), sv = sin_rev(p);
        br[q] = arj[j] * c - aij[j] * sv;
        bi[q] = arj[j] * sv + aij[j] * c;
        sr[q] += br[q]; si[q] += bi[q];
      }
      const size_t o = bfbase + ((size_t)j * SLEN + s0) * 2;
      if (o + 8 <= cap) {
        store_nt4(out + o,     br[0], bi[0], br[1], bi[1]);
        store_nt4(out + o + 4, br[2], bi[2], br[3], bi[3]);
      }
    }
    const size_t o = (size_t)41943040 + ((size_t)b * SLEN + s0) * 2;
    if (o + 8 <= cap) {
      store_nt4(out + o,     xv.x - sr[0], -si[0], xv.y - sr[1], -si[1]);
      store_nt4(out + o + 4, xv.z - sr[2], -si[2], xv.w - sr[3], -si[3]);
    }
  }
}

extern "C" void kernel_launch(void* const* d_in, const int* in_sizes, int n_in,
                              void* d_out, int out_size, void* d_ws, size_t ws_size,
                              hipStream_t stream) {
  const float* x = (const float*)d_in[0];
  float* out = (float*)d_out;
  fft_topk<<<NB, 1024, 0, stream>>>(x);
  gen<<<NB * 8, 256, 0, stream>>>(x, out, (size_t)out_size);
}